// Round 4
// baseline (406.285 us; speedup 1.0000x reference)
//
#include <hip/hip_runtime.h>
#include <math.h>

// ---------------------------------------------------------------------------
// SimVQ forward, round 4: occupancy round.
//  - coarse GEMM __launch_bounds__(256,3) -> (256,5): 5 resident blocks/CU
//    (LDS 5x32KiB = 160KiB exact; VGPR cap 102 >= 72 used). The single-buffer
//    stage->drain->compute structure hides load latency ONLY via cross-block
//    overlap (m114); 3 blocks/CU was the binding cap (Occupancy 31.6%, both
//    pipes <30%).
// ---------------------------------------------------------------------------

typedef _Float16 f16;
typedef _Float16 f16x8 __attribute__((ext_vector_type(8)));
typedef _Float16 f16x4 __attribute__((ext_vector_type(4)));
typedef short s16x8 __attribute__((ext_vector_type(8)));
typedef float f32x4 __attribute__((ext_vector_type(4)));
typedef unsigned int u32;
typedef unsigned long long u64;
typedef unsigned short ushort_t;

#define INV2048 (1.0f/2048.0f)
#define MARGIN  0.010f

// ---- workspace layout (bytes) ----
#define OFF_Q    0u            // 16384*512*4 = 33554432
#define OFF_EHI  33554432u     // emb hi f16 (dead after codebook GEMM)
#define OFF_ELO  50331648u     // emb lo f16 (dead after codebook GEMM)
#define OFF_WHI  67108864u     // 512*512*2
#define OFF_WLO  67633152u
#define OFF_CB   68157440u     // codebook bf16 normalized, 16384*512*2
#define OFF_ZB   84934656u     // z normalized bf16, 8192*512*2
#define OFF_RL   93323264u     // 8192*4 per-row loss
#define OFF_PK   OFF_EHI       // alias: cand keys, 8192*128*4*8 = 33554432

__device__ __forceinline__ void gload_lds16(const void* g, void* l) {
  __builtin_amdgcn_global_load_lds(
      (const __attribute__((address_space(1))) u32*)g,
      (__attribute__((address_space(3))) u32*)l, 16, 0, 0);
}

// Stage 128 x 64 elems of 2-byte data (global row stride 1024B) into LDS.
// XOR swizzle on the GLOBAL source (both-sides rule); LDS dest linear.
__device__ __forceinline__ void stage_tile(const void* __restrict__ src, int row0,
                                           int kt, char* lds, int tid) {
#pragma unroll
  for (int i = 0; i < 4; ++i) {
    int lin = i * 256 + tid;      // 16B chunk index
    int row = lin >> 3;           // 8 chunks per 128B row
    int slot = lin & 7;
    int k8 = slot ^ (row & 7);
    const char* g = (const char*)src + (((size_t)(row0 + row)) << 10)
                    + (size_t)(kt * 128 + k8 * 16);
    gload_lds16(g, lds + lin * 16);
  }
}

// ---- u64 sort keys: high 32 = ordered float, low 32 = ~idx (tie->low idx) ----
__device__ __forceinline__ u64 make_key(float v, int idx) {
  u32 b = __float_as_uint(v);
  u32 m = (u32)((int)b >> 31) | 0x80000000u;
  return ((u64)(b ^ m) << 32) | (u32)(0x7FFFFFFF - idx);
}
__device__ __forceinline__ float key_val(u64 k) {
  u32 o = (u32)(k >> 32);
  u32 m = (o & 0x80000000u) ? 0x80000000u : 0xFFFFFFFFu;
  return __uint_as_float(o ^ m);   // key 0 -> NaN (always fails >= thresh)
}
__device__ __forceinline__ int key_idx(u64 k) {
  return 0x7FFFFFFF - (int)(u32)(k & 0xFFFFFFFFu);
}
__device__ __forceinline__ u64 umax64(u64 a, u64 b) { return a > b ? a : b; }

// ======================= exact fp16 hi/lo GEMM (codebook) ====================
#define LDS_AHI 0
#define LDS_ALO 16384
#define LDS_BHI 32768
#define LDS_BLO 49152

__global__ __launch_bounds__(256, 2) void k_gemm_codebook(
    const f16* __restrict__ Ahi, const f16* __restrict__ Alo,
    const f16* __restrict__ Bhi, const f16* __restrict__ Blo,
    const float* __restrict__ bias, float* __restrict__ Q) {
  __shared__ __align__(16) char lds[65536];
  f32x4 hh[4][4], xx[4][4];
  const int tid = threadIdx.x;
  const int m0 = blockIdx.y * 128;
  const int n0 = blockIdx.x * 128;
  const int l = tid & 63;
  const int wid = tid >> 6;
  const int wr = (wid >> 1) * 64;
  const int wc = (wid & 1) * 64;
  const int r7 = (l & 15) & 7;   // low 3 bits of every fragment row (mf*16 == 0 mod 8)

#pragma unroll
  for (int a = 0; a < 4; ++a)
#pragma unroll
    for (int b = 0; b < 4; ++b) {
      hh[a][b] = (f32x4){0.f, 0.f, 0.f, 0.f};
      xx[a][b] = (f32x4){0.f, 0.f, 0.f, 0.f};
    }

  for (int kt = 0; kt < 8; ++kt) {
    stage_tile(Ahi, m0, kt, lds + LDS_AHI, tid);
    stage_tile(Alo, m0, kt, lds + LDS_ALO, tid);
    stage_tile(Bhi, n0, kt, lds + LDS_BHI, tid);
    stage_tile(Blo, n0, kt, lds + LDS_BLO, tid);
    __syncthreads();
#pragma unroll
    for (int ks = 0; ks < 2; ++ks) {
      const int kg = ks * 4 + (l >> 4);
      const int s = (kg ^ r7) * 16;
      const char* pa = lds + (wr + (l & 15)) * 128 + s;   // + mf*2048 immediates
      const char* pb = lds + (wc + (l & 15)) * 128 + s;   // + nf*2048 immediates
      f16x8 ahi[4], alo[4];
#pragma unroll
      for (int mf = 0; mf < 4; ++mf) {
        ahi[mf] = *(const f16x8*)(pa + LDS_AHI + mf * 2048);
        alo[mf] = *(const f16x8*)(pa + LDS_ALO + mf * 2048);
      }
#pragma unroll
      for (int nf = 0; nf < 4; ++nf) {
        f16x8 bhi = *(const f16x8*)(pb + LDS_BHI + nf * 2048);
        f16x8 blo = *(const f16x8*)(pb + LDS_BLO + nf * 2048);
#pragma unroll
        for (int mf = 0; mf < 4; ++mf) {
          hh[mf][nf] = __builtin_amdgcn_mfma_f32_16x16x32_f16(ahi[mf], bhi, hh[mf][nf], 0, 0, 0);
          xx[mf][nf] = __builtin_amdgcn_mfma_f32_16x16x32_f16(ahi[mf], blo, xx[mf][nf], 0, 0, 0);
          xx[mf][nf] = __builtin_amdgcn_mfma_f32_16x16x32_f16(alo[mf], bhi, xx[mf][nf], 0, 0, 0);
        }
      }
    }
    __syncthreads();
  }

#pragma unroll
  for (int mf = 0; mf < 4; ++mf)
#pragma unroll
    for (int nf = 0; nf < 4; ++nf)
#pragma unroll
      for (int j = 0; j < 4; ++j) {
        int row = m0 + wr + mf * 16 + (l >> 4) * 4 + j;
        int col = n0 + wc + nf * 16 + (l & 15);
        Q[(size_t)row * 512 + col] = hh[mf][nf][j] + xx[mf][nf][j] * INV2048 + bias[col];
      }
}

// ======================= bf16 coarse GEMM + candidate epilogue ===============
// A = codebook bf16 [16384][512] (rows), B = z_n bf16 [8192][512] (cols).
// C[code][z]. Epilogue: per z-col chunk max, then collect values within
// MARGIN of it (provable superset of within-margin-of-global-max candidates).
__global__ __launch_bounds__(256, 5) void k_gemm_coarse(
    const ushort_t* __restrict__ CB, const ushort_t* __restrict__ ZB,
    u64* __restrict__ pk) {
  __shared__ __align__(16) char lds[32768];
  f32x4 acc[4][4];
  const int tid = threadIdx.x;
  const int cb0 = blockIdx.x * 128;   // code rows
  const int zb0 = blockIdx.y * 128;   // z cols
  const int l = tid & 63;
  const int wid = tid >> 6;
  const int wr = (wid >> 1);          // code half (0/1)
  const int wc = (wid & 1);          // z half (0/1)
  const int r7 = (l & 15) & 7;

#pragma unroll
  for (int a = 0; a < 4; ++a)
#pragma unroll
    for (int b = 0; b < 4; ++b) acc[a][b] = (f32x4){0.f, 0.f, 0.f, 0.f};

  for (int kt = 0; kt < 8; ++kt) {
    stage_tile(CB, cb0, kt, lds, tid);           // A tile 16KB
    stage_tile(ZB, zb0, kt, lds + 16384, tid);   // B tile 16KB
    __syncthreads();
#pragma unroll
    for (int ks = 0; ks < 2; ++ks) {
      const int kg = ks * 4 + (l >> 4);
      const int s = (kg ^ r7) * 16;
      const char* pa = lds + (wr * 64 + (l & 15)) * 128 + s;
      const char* pb = lds + 16384 + (wc * 64 + (l & 15)) * 128 + s;
      s16x8 af[4];
#pragma unroll
      for (int mf = 0; mf < 4; ++mf)
        af[mf] = *(const s16x8*)(pa + mf * 2048);
#pragma unroll
      for (int nf = 0; nf < 4; ++nf) {
        s16x8 bf = *(const s16x8*)(pb + nf * 2048);
#pragma unroll
        for (int mf = 0; mf < 4; ++mf)
          acc[mf][nf] = __builtin_amdgcn_mfma_f32_16x16x32_bf16(af[mf], bf, acc[mf][nf], 0, 0, 0);
      }
    }
    __syncthreads();
  }

  // ---- epilogue ----
  // lane l holds, for each nf, 16 values (mf x j): z-col wc*64+nf*16+(l&15),
  // code cb0 + wr*64 + mf*16 + (l>>4)*4 + j.
  float* cmax = (float*)lds;            // [128 cols][2 wr halves]
  u32* cnt = (u32*)(lds + 1024);        // [128]
  u64* slots = (u64*)(lds + 2048);      // [128][4]

  // phase A: per-(col, wr-half) max, LDS init
  float cm[4];
#pragma unroll
  for (int nf = 0; nf < 4; ++nf) {
    float m = acc[0][nf][0];
#pragma unroll
    for (int mf = 0; mf < 4; ++mf)
#pragma unroll
      for (int j = 0; j < 4; ++j) m = fmaxf(m, acc[mf][nf][j]);
    m = fmaxf(m, __shfl_xor(m, 16, 64));
    m = fmaxf(m, __shfl_xor(m, 32, 64));
    cm[nf] = m;
  }
  if (tid < 128) cnt[tid] = 0;
  slots[tid] = 0;
  slots[tid + 256] = 0;
  if ((l >> 4) == 0) {
#pragma unroll
    for (int nf = 0; nf < 4; ++nf)
      cmax[(wc * 64 + nf * 16 + l) * 2 + wr] = cm[nf];
  }
  __syncthreads();

  // phase B: collect values within MARGIN of full chunk max
#pragma unroll
  for (int nf = 0; nf < 4; ++nf) {
    int col = wc * 64 + nf * 16 + (l & 15);
    float thresh = fmaxf(cmax[col * 2], cmax[col * 2 + 1]) - MARGIN;
#pragma unroll
    for (int mf = 0; mf < 4; ++mf)
#pragma unroll
      for (int j = 0; j < 4; ++j) {
        float v = acc[mf][nf][j];
        if (v >= thresh) {
          int code = cb0 + wr * 64 + mf * 16 + ((l >> 4) << 2) + j;
          u32 p = atomicAdd(&cnt[col], 1u);
          if (p < 4) slots[col * 4 + p] = make_key(v, code);
        }
      }
  }
  __syncthreads();

  // phase C: write out 4 slots per col
  if (tid < 128) {
    size_t base = (((size_t)(zb0 + tid)) * 128 + blockIdx.x) * 4;
#pragma unroll
    for (int s = 0; s < 4; ++s) pk[base + s] = slots[tid * 4 + s];
  }
}

// ---- f32 -> fp16 hi/lo split ----
__global__ __launch_bounds__(256) void k_split(const float* __restrict__ src,
                                               f16* __restrict__ hi,
                                               f16* __restrict__ lo, int n4) {
  int i = blockIdx.x * 256 + threadIdx.x;
  if (i >= n4) return;
  const float4 v = ((const float4*)src)[i];
  f16 h0 = (f16)v.x, h1 = (f16)v.y, h2 = (f16)v.z, h3 = (f16)v.w;
  ((f16x4*)hi)[i] = (f16x4){h0, h1, h2, h3};
  ((f16x4*)lo)[i] = (f16x4){(f16)((v.x - (float)h0) * 2048.0f),
                            (f16)((v.y - (float)h1) * 2048.0f),
                            (f16)((v.z - (float)h2) * 2048.0f),
                            (f16)((v.w - (float)h3) * 2048.0f)};
}

__device__ __forceinline__ ushort_t f2bf_rne(float f) {
  u32 b = __float_as_uint(f);
  b += 0x7FFFu + ((b >> 16) & 1u);
  return (ushort_t)(b >> 16);
}

// ---- row L2-normalize src -> bf16 dst. One block per row, 512 cols ----
__global__ __launch_bounds__(256) void k_norm_bf16(const float* __restrict__ src,
                                                   ushort_t* __restrict__ dst) {
  __shared__ float red[256];
  const int row = blockIdx.x, t = threadIdx.x;
  float q0 = src[(size_t)row * 512 + t];
  float q1 = src[(size_t)row * 512 + t + 256];
  red[t] = q0 * q0 + q1 * q1;
  __syncthreads();
  for (int s = 128; s > 0; s >>= 1) {
    if (t < s) red[t] += red[t + s];
    __syncthreads();
  }
  float inv = 1.0f / fmaxf(sqrtf(red[0]), 1e-12f);
  dst[(size_t)row * 512 + t] = f2bf_rne(q0 * inv);
  dst[(size_t)row * 512 + t + 256] = f2bf_rne(q1 * inv);
}

// ---- candidate rescore (f64) + gather + straight-through + row loss ----
__global__ __launch_bounds__(256) void k_rescore_gather(
    const u64* __restrict__ pk, const float* __restrict__ Q,
    const float* __restrict__ z, float* __restrict__ outq,
    float* __restrict__ outidx, float* __restrict__ rloss) {
  __shared__ float sz[512];
  __shared__ double redd[8];
  __shared__ u64 redk[4];
  __shared__ int cand[64];
  __shared__ int ccount;
  const int row = blockIdx.x, t = threadIdx.x;

  sz[t] = z[(size_t)row * 512 + t];
  sz[t + 256] = z[(size_t)row * 512 + t + 256];
  if (t == 0) ccount = 0;

  u64 k1 = pk[(size_t)row * 512 + t * 2];
  u64 k2 = pk[(size_t)row * 512 + t * 2 + 1];
  u64 km = umax64(k1, k2);
  for (int m = 1; m < 64; m <<= 1)
    km = umax64(km, (u64)__shfl_xor((long long)km, m));
  if ((t & 63) == 0) redk[t >> 6] = km;
  __syncthreads();
  u64 gk = umax64(umax64(redk[0], redk[1]), umax64(redk[2], redk[3]));
  float thresh = key_val(gk) - MARGIN;

  if (key_val(k1) >= thresh) { int p = atomicAdd(&ccount, 1); if (p < 64) cand[p] = key_idx(k1); }
  if (key_val(k2) >= thresh) { int p = atomicAdd(&ccount, 1); if (p < 64) cand[p] = key_idx(k2); }
  __syncthreads();
  int nc = ccount < 64 ? ccount : 64;

  double bs = -1e300;
  int bi = 0x7FFFFFFF;
  for (int c = 0; c < nc; ++c) {
    int code = cand[c];
    const float* Qr = Q + (size_t)code * 512;
    double dotp = 0.0, qq = 0.0;
#pragma unroll
    for (int h = 0; h < 2; ++h) {
      int d = t + h * 256;
      double qv = (double)Qr[d];
      dotp += (double)sz[d] * qv;
      qq += qv * qv;
    }
    for (int m = 1; m < 64; m <<= 1) {
      dotp += __shfl_xor(dotp, m);
      qq += __shfl_xor(qq, m);
    }
    if ((t & 63) == 0) { redd[t >> 6] = dotp; redd[4 + (t >> 6)] = qq; }
    __syncthreads();
    double dsum = redd[0] + redd[1] + redd[2] + redd[3];
    double qsum = redd[4] + redd[5] + redd[6] + redd[7];
    double s = dsum / fmax(sqrt(qsum), 1e-12);
    if (s > bs || (s == bs && code < bi)) { bs = s; bi = code; }
    __syncthreads();
  }

  const float* Qb = Q + (size_t)bi * 512;
  double lsum = 0.0;
#pragma unroll
  for (int h = 0; h < 2; ++h) {
    int d = t + h * 256;
    float qv = Qb[d], zv = sz[d];
    outq[(size_t)row * 512 + d] = zv + (qv - zv);
    float df = qv - zv;
    lsum += (double)df * (double)df;
  }
  for (int m = 1; m < 64; m <<= 1) lsum += __shfl_xor(lsum, m);
  if ((t & 63) == 0) redd[t >> 6] = lsum;
  __syncthreads();
  if (t == 0) {
    rloss[row] = (float)(redd[0] + redd[1] + redd[2] + redd[3]);
    outidx[row] = (float)bi;
  }
}

__global__ __launch_bounds__(256) void k_loss_final(const float* __restrict__ rloss,
                                                    float* __restrict__ out_loss) {
  __shared__ float sl[256];
  int t = threadIdx.x;
  float s = 0.f;
#pragma unroll
  for (int i = 0; i < 32; ++i) s += rloss[t + i * 256];
  sl[t] = s;
  __syncthreads();
  for (int k = 128; k > 0; k >>= 1) {
    if (t < k) sl[t] += sl[t + k];
    __syncthreads();
  }
  if (t == 0) out_loss[0] = 1.25f * sl[0] / 4194304.0f;
}

extern "C" void kernel_launch(void* const* d_in, const int* in_sizes, int n_in,
                              void* d_out, int out_size, void* d_ws, size_t ws_size,
                              hipStream_t stream) {
  const float* z = (const float*)d_in[0];
  const float* emb = (const float*)d_in[1];
  const float* pw = (const float*)d_in[2];
  const float* pb = (const float*)d_in[3];

  char* ws = (char*)d_ws;
  float* Q = (float*)(ws + OFF_Q);
  f16* ehi = (f16*)(ws + OFF_EHI);
  f16* elo = (f16*)(ws + OFF_ELO);
  f16* whi = (f16*)(ws + OFF_WHI);
  f16* wlo = (f16*)(ws + OFF_WLO);
  ushort_t* cb = (ushort_t*)(ws + OFF_CB);
  ushort_t* zb = (ushort_t*)(ws + OFF_ZB);
  u64* pk = (u64*)(ws + OFF_PK);
  float* rloss = (float*)(ws + OFF_RL);

  float* outq = (float*)d_out;
  float* outloss = outq + 4194304;
  float* outidx = outq + 4194305;

  k_split<<<8192, 256, 0, stream>>>(emb, ehi, elo, 2097152);
  k_split<<<256, 256, 0, stream>>>(pw, whi, wlo, 65536);
  k_norm_bf16<<<8192, 256, 0, stream>>>(z, zb);                    // z_n bf16
  k_gemm_codebook<<<dim3(4, 128), 256, 0, stream>>>(ehi, elo, whi, wlo, pb, Q);
  k_norm_bf16<<<16384, 256, 0, stream>>>(Q, cb);                   // c_n bf16
  k_gemm_coarse<<<dim3(128, 64), 256, 0, stream>>>(cb, zb, pk);
  k_rescore_gather<<<8192, 256, 0, stream>>>(pk, Q, z, outq, outidx, rloss);
  k_loss_final<<<1, 256, 0, stream>>>(rloss, outloss);
}

// Round 5
// 286.071 us; speedup vs baseline: 1.4202x; 1.4202x over previous
//
#include <hip/hip_runtime.h>
#include <math.h>

// ---------------------------------------------------------------------------
// SimVQ forward, round 5: fix the round-4 spill cliff.
//  - coarse GEMM __launch_bounds__(256,5) -> (256,4). (256,5) forced VGPR=48
//    < the 64-reg accumulator file -> scratch spill (WRITE_SIZE 32KB->394MB,
//    dur 205->324us). (256,4) caps VGPR at 128 >= ~100-reg working set:
//    no spill, 16 waves/CU (vs 12 at round 3's (256,3)).
// ---------------------------------------------------------------------------

typedef _Float16 f16;
typedef _Float16 f16x8 __attribute__((ext_vector_type(8)));
typedef _Float16 f16x4 __attribute__((ext_vector_type(4)));
typedef short s16x8 __attribute__((ext_vector_type(8)));
typedef float f32x4 __attribute__((ext_vector_type(4)));
typedef unsigned int u32;
typedef unsigned long long u64;
typedef unsigned short ushort_t;

#define INV2048 (1.0f/2048.0f)
#define MARGIN  0.010f

// ---- workspace layout (bytes) ----
#define OFF_Q    0u            // 16384*512*4 = 33554432
#define OFF_EHI  33554432u     // emb hi f16 (dead after codebook GEMM)
#define OFF_ELO  50331648u     // emb lo f16 (dead after codebook GEMM)
#define OFF_WHI  67108864u     // 512*512*2
#define OFF_WLO  67633152u
#define OFF_CB   68157440u     // codebook bf16 normalized, 16384*512*2
#define OFF_ZB   84934656u     // z normalized bf16, 8192*512*2
#define OFF_RL   93323264u     // 8192*4 per-row loss
#define OFF_PK   OFF_EHI       // alias: cand keys, 8192*128*4*8 = 33554432

__device__ __forceinline__ void gload_lds16(const void* g, void* l) {
  __builtin_amdgcn_global_load_lds(
      (const __attribute__((address_space(1))) u32*)g,
      (__attribute__((address_space(3))) u32*)l, 16, 0, 0);
}

// Stage 128 x 64 elems of 2-byte data (global row stride 1024B) into LDS.
// XOR swizzle on the GLOBAL source (both-sides rule); LDS dest linear.
__device__ __forceinline__ void stage_tile(const void* __restrict__ src, int row0,
                                           int kt, char* lds, int tid) {
#pragma unroll
  for (int i = 0; i < 4; ++i) {
    int lin = i * 256 + tid;      // 16B chunk index
    int row = lin >> 3;           // 8 chunks per 128B row
    int slot = lin & 7;
    int k8 = slot ^ (row & 7);
    const char* g = (const char*)src + (((size_t)(row0 + row)) << 10)
                    + (size_t)(kt * 128 + k8 * 16);
    gload_lds16(g, lds + lin * 16);
  }
}

// ---- u64 sort keys: high 32 = ordered float, low 32 = ~idx (tie->low idx) ----
__device__ __forceinline__ u64 make_key(float v, int idx) {
  u32 b = __float_as_uint(v);
  u32 m = (u32)((int)b >> 31) | 0x80000000u;
  return ((u64)(b ^ m) << 32) | (u32)(0x7FFFFFFF - idx);
}
__device__ __forceinline__ float key_val(u64 k) {
  u32 o = (u32)(k >> 32);
  u32 m = (o & 0x80000000u) ? 0x80000000u : 0xFFFFFFFFu;
  return __uint_as_float(o ^ m);   // key 0 -> NaN (always fails >= thresh)
}
__device__ __forceinline__ int key_idx(u64 k) {
  return 0x7FFFFFFF - (int)(u32)(k & 0xFFFFFFFFu);
}
__device__ __forceinline__ u64 umax64(u64 a, u64 b) { return a > b ? a : b; }

// ======================= exact fp16 hi/lo GEMM (codebook) ====================
#define LDS_AHI 0
#define LDS_ALO 16384
#define LDS_BHI 32768
#define LDS_BLO 49152

__global__ __launch_bounds__(256, 2) void k_gemm_codebook(
    const f16* __restrict__ Ahi, const f16* __restrict__ Alo,
    const f16* __restrict__ Bhi, const f16* __restrict__ Blo,
    const float* __restrict__ bias, float* __restrict__ Q) {
  __shared__ __align__(16) char lds[65536];
  f32x4 hh[4][4], xx[4][4];
  const int tid = threadIdx.x;
  const int m0 = blockIdx.y * 128;
  const int n0 = blockIdx.x * 128;
  const int l = tid & 63;
  const int wid = tid >> 6;
  const int wr = (wid >> 1) * 64;
  const int wc = (wid & 1) * 64;
  const int r7 = (l & 15) & 7;   // low 3 bits of every fragment row (mf*16 == 0 mod 8)

#pragma unroll
  for (int a = 0; a < 4; ++a)
#pragma unroll
    for (int b = 0; b < 4; ++b) {
      hh[a][b] = (f32x4){0.f, 0.f, 0.f, 0.f};
      xx[a][b] = (f32x4){0.f, 0.f, 0.f, 0.f};
    }

  for (int kt = 0; kt < 8; ++kt) {
    stage_tile(Ahi, m0, kt, lds + LDS_AHI, tid);
    stage_tile(Alo, m0, kt, lds + LDS_ALO, tid);
    stage_tile(Bhi, n0, kt, lds + LDS_BHI, tid);
    stage_tile(Blo, n0, kt, lds + LDS_BLO, tid);
    __syncthreads();
#pragma unroll
    for (int ks = 0; ks < 2; ++ks) {
      const int kg = ks * 4 + (l >> 4);
      const int s = (kg ^ r7) * 16;
      const char* pa = lds + (wr + (l & 15)) * 128 + s;   // + mf*2048 immediates
      const char* pb = lds + (wc + (l & 15)) * 128 + s;   // + nf*2048 immediates
      f16x8 ahi[4], alo[4];
#pragma unroll
      for (int mf = 0; mf < 4; ++mf) {
        ahi[mf] = *(const f16x8*)(pa + LDS_AHI + mf * 2048);
        alo[mf] = *(const f16x8*)(pa + LDS_ALO + mf * 2048);
      }
#pragma unroll
      for (int nf = 0; nf < 4; ++nf) {
        f16x8 bhi = *(const f16x8*)(pb + LDS_BHI + nf * 2048);
        f16x8 blo = *(const f16x8*)(pb + LDS_BLO + nf * 2048);
#pragma unroll
        for (int mf = 0; mf < 4; ++mf) {
          hh[mf][nf] = __builtin_amdgcn_mfma_f32_16x16x32_f16(ahi[mf], bhi, hh[mf][nf], 0, 0, 0);
          xx[mf][nf] = __builtin_amdgcn_mfma_f32_16x16x32_f16(ahi[mf], blo, xx[mf][nf], 0, 0, 0);
          xx[mf][nf] = __builtin_amdgcn_mfma_f32_16x16x32_f16(alo[mf], bhi, xx[mf][nf], 0, 0, 0);
        }
      }
    }
    __syncthreads();
  }

#pragma unroll
  for (int mf = 0; mf < 4; ++mf)
#pragma unroll
    for (int nf = 0; nf < 4; ++nf)
#pragma unroll
      for (int j = 0; j < 4; ++j) {
        int row = m0 + wr + mf * 16 + (l >> 4) * 4 + j;
        int col = n0 + wc + nf * 16 + (l & 15);
        Q[(size_t)row * 512 + col] = hh[mf][nf][j] + xx[mf][nf][j] * INV2048 + bias[col];
      }
}

// ======================= bf16 coarse GEMM + candidate epilogue ===============
// A = codebook bf16 [16384][512] (rows), B = z_n bf16 [8192][512] (cols).
// C[code][z]. Epilogue: per z-col chunk max, then collect values within
// MARGIN of it (provable superset of within-margin-of-global-max candidates).
__global__ __launch_bounds__(256, 4) void k_gemm_coarse(
    const ushort_t* __restrict__ CB, const ushort_t* __restrict__ ZB,
    u64* __restrict__ pk) {
  __shared__ __align__(16) char lds[32768];
  f32x4 acc[4][4];
  const int tid = threadIdx.x;
  const int cb0 = blockIdx.x * 128;   // code rows
  const int zb0 = blockIdx.y * 128;   // z cols
  const int l = tid & 63;
  const int wid = tid >> 6;
  const int wr = (wid >> 1);          // code half (0/1)
  const int wc = (wid & 1);           // z half (0/1)
  const int r7 = (l & 15) & 7;

#pragma unroll
  for (int a = 0; a < 4; ++a)
#pragma unroll
    for (int b = 0; b < 4; ++b) acc[a][b] = (f32x4){0.f, 0.f, 0.f, 0.f};

  for (int kt = 0; kt < 8; ++kt) {
    stage_tile(CB, cb0, kt, lds, tid);           // A tile 16KB
    stage_tile(ZB, zb0, kt, lds + 16384, tid);   // B tile 16KB
    __syncthreads();
#pragma unroll
    for (int ks = 0; ks < 2; ++ks) {
      const int kg = ks * 4 + (l >> 4);
      const int s = (kg ^ r7) * 16;
      const char* pa = lds + (wr * 64 + (l & 15)) * 128 + s;
      const char* pb = lds + 16384 + (wc * 64 + (l & 15)) * 128 + s;
      s16x8 af[4];
#pragma unroll
      for (int mf = 0; mf < 4; ++mf)
        af[mf] = *(const s16x8*)(pa + mf * 2048);
#pragma unroll
      for (int nf = 0; nf < 4; ++nf) {
        s16x8 bf = *(const s16x8*)(pb + nf * 2048);
#pragma unroll
        for (int mf = 0; mf < 4; ++mf)
          acc[mf][nf] = __builtin_amdgcn_mfma_f32_16x16x32_bf16(af[mf], bf, acc[mf][nf], 0, 0, 0);
      }
    }
    __syncthreads();
  }

  // ---- epilogue ----
  // lane l holds, for each nf, 16 values (mf x j): z-col wc*64+nf*16+(l&15),
  // code cb0 + wr*64 + mf*16 + (l>>4)*4 + j.
  float* cmax = (float*)lds;            // [128 cols][2 wr halves]
  u32* cnt = (u32*)(lds + 1024);        // [128]
  u64* slots = (u64*)(lds + 2048);      // [128][4]

  // phase A: per-(col, wr-half) max, LDS init
  float cm[4];
#pragma unroll
  for (int nf = 0; nf < 4; ++nf) {
    float m = acc[0][nf][0];
#pragma unroll
    for (int mf = 0; mf < 4; ++mf)
#pragma unroll
      for (int j = 0; j < 4; ++j) m = fmaxf(m, acc[mf][nf][j]);
    m = fmaxf(m, __shfl_xor(m, 16, 64));
    m = fmaxf(m, __shfl_xor(m, 32, 64));
    cm[nf] = m;
  }
  if (tid < 128) cnt[tid] = 0;
  slots[tid] = 0;
  slots[tid + 256] = 0;
  if ((l >> 4) == 0) {
#pragma unroll
    for (int nf = 0; nf < 4; ++nf)
      cmax[(wc * 64 + nf * 16 + l) * 2 + wr] = cm[nf];
  }
  __syncthreads();

  // phase B: collect values within MARGIN of full chunk max
#pragma unroll
  for (int nf = 0; nf < 4; ++nf) {
    int col = wc * 64 + nf * 16 + (l & 15);
    float thresh = fmaxf(cmax[col * 2], cmax[col * 2 + 1]) - MARGIN;
#pragma unroll
    for (int mf = 0; mf < 4; ++mf)
#pragma unroll
      for (int j = 0; j < 4; ++j) {
        float v = acc[mf][nf][j];
        if (v >= thresh) {
          int code = cb0 + wr * 64 + mf * 16 + ((l >> 4) << 2) + j;
          u32 p = atomicAdd(&cnt[col], 1u);
          if (p < 4) slots[col * 4 + p] = make_key(v, code);
        }
      }
  }
  __syncthreads();

  // phase C: write out 4 slots per col
  if (tid < 128) {
    size_t base = (((size_t)(zb0 + tid)) * 128 + blockIdx.x) * 4;
#pragma unroll
    for (int s = 0; s < 4; ++s) pk[base + s] = slots[tid * 4 + s];
  }
}

// ---- f32 -> fp16 hi/lo split ----
__global__ __launch_bounds__(256) void k_split(const float* __restrict__ src,
                                               f16* __restrict__ hi,
                                               f16* __restrict__ lo, int n4) {
  int i = blockIdx.x * 256 + threadIdx.x;
  if (i >= n4) return;
  const float4 v = ((const float4*)src)[i];
  f16 h0 = (f16)v.x, h1 = (f16)v.y, h2 = (f16)v.z, h3 = (f16)v.w;
  ((f16x4*)hi)[i] = (f16x4){h0, h1, h2, h3};
  ((f16x4*)lo)[i] = (f16x4){(f16)((v.x - (float)h0) * 2048.0f),
                            (f16)((v.y - (float)h1) * 2048.0f),
                            (f16)((v.z - (float)h2) * 2048.0f),
                            (f16)((v.w - (float)h3) * 2048.0f)};
}

__device__ __forceinline__ ushort_t f2bf_rne(float f) {
  u32 b = __float_as_uint(f);
  b += 0x7FFFu + ((b >> 16) & 1u);
  return (ushort_t)(b >> 16);
}

// ---- row L2-normalize src -> bf16 dst. One block per row, 512 cols ----
__global__ __launch_bounds__(256) void k_norm_bf16(const float* __restrict__ src,
                                                   ushort_t* __restrict__ dst) {
  __shared__ float red[256];
  const int row = blockIdx.x, t = threadIdx.x;
  float q0 = src[(size_t)row * 512 + t];
  float q1 = src[(size_t)row * 512 + t + 256];
  red[t] = q0 * q0 + q1 * q1;
  __syncthreads();
  for (int s = 128; s > 0; s >>= 1) {
    if (t < s) red[t] += red[t + s];
    __syncthreads();
  }
  float inv = 1.0f / fmaxf(sqrtf(red[0]), 1e-12f);
  dst[(size_t)row * 512 + t] = f2bf_rne(q0 * inv);
  dst[(size_t)row * 512 + t + 256] = f2bf_rne(q1 * inv);
}

// ---- candidate rescore (f64) + gather + straight-through + row loss ----
__global__ __launch_bounds__(256) void k_rescore_gather(
    const u64* __restrict__ pk, const float* __restrict__ Q,
    const float* __restrict__ z, float* __restrict__ outq,
    float* __restrict__ outidx, float* __restrict__ rloss) {
  __shared__ float sz[512];
  __shared__ double redd[8];
  __shared__ u64 redk[4];
  __shared__ int cand[64];
  __shared__ int ccount;
  const int row = blockIdx.x, t = threadIdx.x;

  sz[t] = z[(size_t)row * 512 + t];
  sz[t + 256] = z[(size_t)row * 512 + t + 256];
  if (t == 0) ccount = 0;

  u64 k1 = pk[(size_t)row * 512 + t * 2];
  u64 k2 = pk[(size_t)row * 512 + t * 2 + 1];
  u64 km = umax64(k1, k2);
  for (int m = 1; m < 64; m <<= 1)
    km = umax64(km, (u64)__shfl_xor((long long)km, m));
  if ((t & 63) == 0) redk[t >> 6] = km;
  __syncthreads();
  u64 gk = umax64(umax64(redk[0], redk[1]), umax64(redk[2], redk[3]));
  float thresh = key_val(gk) - MARGIN;

  if (key_val(k1) >= thresh) { int p = atomicAdd(&ccount, 1); if (p < 64) cand[p] = key_idx(k1); }
  if (key_val(k2) >= thresh) { int p = atomicAdd(&ccount, 1); if (p < 64) cand[p] = key_idx(k2); }
  __syncthreads();
  int nc = ccount < 64 ? ccount : 64;

  double bs = -1e300;
  int bi = 0x7FFFFFFF;
  for (int c = 0; c < nc; ++c) {
    int code = cand[c];
    const float* Qr = Q + (size_t)code * 512;
    double dotp = 0.0, qq = 0.0;
#pragma unroll
    for (int h = 0; h < 2; ++h) {
      int d = t + h * 256;
      double qv = (double)Qr[d];
      dotp += (double)sz[d] * qv;
      qq += qv * qv;
    }
    for (int m = 1; m < 64; m <<= 1) {
      dotp += __shfl_xor(dotp, m);
      qq += __shfl_xor(qq, m);
    }
    if ((t & 63) == 0) { redd[t >> 6] = dotp; redd[4 + (t >> 6)] = qq; }
    __syncthreads();
    double dsum = redd[0] + redd[1] + redd[2] + redd[3];
    double qsum = redd[4] + redd[5] + redd[6] + redd[7];
    double s = dsum / fmax(sqrt(qsum), 1e-12);
    if (s > bs || (s == bs && code < bi)) { bs = s; bi = code; }
    __syncthreads();
  }

  const float* Qb = Q + (size_t)bi * 512;
  double lsum = 0.0;
#pragma unroll
  for (int h = 0; h < 2; ++h) {
    int d = t + h * 256;
    float qv = Qb[d], zv = sz[d];
    outq[(size_t)row * 512 + d] = zv + (qv - zv);
    float df = qv - zv;
    lsum += (double)df * (double)df;
  }
  for (int m = 1; m < 64; m <<= 1) lsum += __shfl_xor(lsum, m);
  if ((t & 63) == 0) redd[t >> 6] = lsum;
  __syncthreads();
  if (t == 0) {
    rloss[row] = (float)(redd[0] + redd[1] + redd[2] + redd[3]);
    outidx[row] = (float)bi;
  }
}

__global__ __launch_bounds__(256) void k_loss_final(const float* __restrict__ rloss,
                                                    float* __restrict__ out_loss) {
  __shared__ float sl[256];
  int t = threadIdx.x;
  float s = 0.f;
#pragma unroll
  for (int i = 0; i < 32; ++i) s += rloss[t + i * 256];
  sl[t] = s;
  __syncthreads();
  for (int k = 128; k > 0; k >>= 1) {
    if (t < k) sl[t] += sl[t + k];
    __syncthreads();
  }
  if (t == 0) out_loss[0] = 1.25f * sl[0] / 4194304.0f;
}

extern "C" void kernel_launch(void* const* d_in, const int* in_sizes, int n_in,
                              void* d_out, int out_size, void* d_ws, size_t ws_size,
                              hipStream_t stream) {
  const float* z = (const float*)d_in[0];
  const float* emb = (const float*)d_in[1];
  const float* pw = (const float*)d_in[2];
  const float* pb = (const float*)d_in[3];

  char* ws = (char*)d_ws;
  float* Q = (float*)(ws + OFF_Q);
  f16* ehi = (f16*)(ws + OFF_EHI);
  f16* elo = (f16*)(ws + OFF_ELO);
  f16* whi = (f16*)(ws + OFF_WHI);
  f16* wlo = (f16*)(ws + OFF_WLO);
  ushort_t* cb = (ushort_t*)(ws + OFF_CB);
  ushort_t* zb = (ushort_t*)(ws + OFF_ZB);
  u64* pk = (u64*)(ws + OFF_PK);
  float* rloss = (float*)(ws + OFF_RL);

  float* outq = (float*)d_out;
  float* outloss = outq + 4194304;
  float* outidx = outq + 4194305;

  k_split<<<8192, 256, 0, stream>>>(emb, ehi, elo, 2097152);
  k_split<<<256, 256, 0, stream>>>(pw, whi, wlo, 65536);
  k_norm_bf16<<<8192, 256, 0, stream>>>(z, zb);                    // z_n bf16
  k_gemm_codebook<<<dim3(4, 128), 256, 0, stream>>>(ehi, elo, whi, wlo, pb, Q);
  k_norm_bf16<<<16384, 256, 0, stream>>>(Q, cb);                   // c_n bf16
  k_gemm_coarse<<<dim3(128, 64), 256, 0, stream>>>(cb, zb, pk);
  k_rescore_gather<<<8192, 256, 0, stream>>>(pk, Q, z, outq, outidx, rloss);
  k_loss_final<<<1, 256, 0, stream>>>(rloss, outloss);
}